// Round 9
// baseline (2088.920 us; speedup 1.0000x reference)
//
#include <hip/hip_runtime.h>
#include <hip/hip_bf16.h>

#define N_NODES 50000
#define N_EDGES 800000
#define DIN_    64
#define EIN_    16
#define H_      300
#define R_OUT   1024
#define G_GR    256
#define DEPTH_  5
#define KPAD    320
#define NPAD    50048   // multiple of 128 >= N_NODES
#define ESLOT   20      // LDS slots per col (16 edges + pad for bank spread, 8B-aligned)

typedef unsigned short ushort_t;
typedef __attribute__((ext_vector_type(8))) short bf16x8;
typedef __attribute__((ext_vector_type(4))) short s16x4;
typedef __attribute__((ext_vector_type(4))) float f32x4;

__device__ __forceinline__ ushort_t f2b(float f) {
  unsigned x = __float_as_uint(f);
  unsigned r = (x + 0x7fffu + ((x >> 16) & 1u)) >> 16;  // RTN-even
  return (ushort_t)r;
}
__device__ __forceinline__ float b2f(ushort_t u) {
  return __uint_as_float((unsigned)u << 16);
}

// ---------------- weight packing (once per call) ----------------
// Pack W1/W2 (fp32 [DEPTH][300][300], k-major) into bf16 frag layout
// Bp[i][kg][n][j] , k = kg*8+j, zero-padded to 320x320.
__global__ void pack_weights(const float* __restrict__ W1, const float* __restrict__ W2,
                             ushort_t* __restrict__ Bp1, ushort_t* __restrict__ Bp2) {
  int idx = blockIdx.x * 256 + threadIdx.x;
  const int per = DEPTH_ * 40 * KPAD * 8;  // 512000
  if (idx >= 2 * per) return;
  const float* W = W1;
  ushort_t* Bp = Bp1;
  int t = idx;
  if (t >= per) { t -= per; W = W2; Bp = Bp2; }
  int j  = t & 7;
  int n  = (t >> 3) % KPAD;
  int kg = ((t >> 3) / KPAD) % 40;
  int i  = t / (40 * KPAD * 8);
  int k  = kg * 8 + j;
  float v = (k < H_ && n < H_) ? W[(i * H_ + k) * H_ + n] : 0.f;
  Bp[t] = f2b(v);
}

// Pack Wpe (fp32 [16][300]) + bpe into frag layout Bpe[kg<4][n<320][j<8],
// K padded to 32 with k==16 row = bpe (bias folded via A k=16 element = 1.0).
__global__ void pack_wpe(const float* __restrict__ Wpe, const float* __restrict__ bpe,
                         ushort_t* __restrict__ Bpe) {
  int t = blockIdx.x * 256 + threadIdx.x;
  if (t >= 4 * KPAD * 8) return;
  int j  = t & 7;
  int n  = (t >> 3) % KPAD;
  int kg = (t >> 3) / KPAD;
  int k  = kg * 8 + j;
  float v = 0.f;
  if (n < H_) {
    if (k < EIN_) v = Wpe[k * H_ + n];
    else if (k == EIN_) v = bpe[n];
  }
  Bpe[t] = f2b(v);
}

// Pack Wpn (fp32 [64][300]) into frag layout Bpn[kg<8][n<320][j<8]
__global__ void pack_wpn(const float* __restrict__ Wpn, ushort_t* __restrict__ Bpn) {
  int t = blockIdx.x * 256 + threadIdx.x;
  if (t >= 8 * KPAD * 8) return;
  int j  = t & 7;
  int n  = (t >> 3) % KPAD;
  int kg = (t >> 3) / KPAD;
  int k  = kg * 8 + j;
  float v = (n < H_) ? Wpn[k * H_ + n] : 0.f;
  Bpn[t] = f2b(v);
}

// ---------------- CSR build (once per call) ----------------
__global__ void hist_deg(const int* __restrict__ dst, int* __restrict__ deg) {
  int e = blockIdx.x * 256 + threadIdx.x;
  if (e < N_EDGES) atomicAdd(deg + dst[e], 1);
}

// single-block exclusive scan of deg[0..N_NODES) -> off, off[N_NODES]=total
__global__ __launch_bounds__(1024) void exscan_kernel(const int* __restrict__ deg,
                                                      int* __restrict__ off) {
  __shared__ int wsum[16];
  __shared__ int carry_s;
  int lane = threadIdx.x & 63;
  int wv = threadIdx.x >> 6;
  if (threadIdx.x == 0) carry_s = 0;
  __syncthreads();
  for (int base = 0; base < N_NODES; base += 1024) {
    int i = base + (int)threadIdx.x;
    int orig = (i < N_NODES) ? deg[i] : 0;
    int v = orig;
#pragma unroll
    for (int s = 1; s < 64; s <<= 1) {
      int u = __shfl_up(v, s);
      if (lane >= s) v += u;
    }
    if (lane == 63) wsum[wv] = v;
    __syncthreads();
    if (wv == 0) {
      int t = (lane < 16) ? wsum[lane] : 0;
#pragma unroll
      for (int s = 1; s < 16; s <<= 1) {
        int u = __shfl_up(t, s);
        if (lane >= s) t += u;
      }
      if (lane < 16) wsum[lane] = t;
    }
    __syncthreads();
    int wbase = (wv > 0) ? wsum[wv - 1] : 0;
    if (i < N_NODES) off[i] = carry_s + wbase + v - orig;
    __syncthreads();
    if (threadIdx.x == 1023) carry_s += wsum[15];
    __syncthreads();
  }
  if (threadIdx.x == 0) off[N_NODES] = carry_s;
}

__global__ void scatter_edges(const int* __restrict__ src, const int* __restrict__ dst,
                              int* __restrict__ cursor, int* __restrict__ csr_src,
                              int* __restrict__ csr_eid) {
  int e = blockIdx.x * 256 + threadIdx.x;
  if (e >= N_EDGES) return;
  int d = dst[e];
  int pos = atomicAdd(cursor + d, 1);
  csr_src[pos] = src[e];
  csr_eid[pos] = e;
}

// ---------------- input projection via MFMA ----------------
__global__ __launch_bounds__(256) void proj_gemm(const float* __restrict__ x,
                                                 const ushort_t* __restrict__ Bpn,
                                                 const float* __restrict__ bpn,
                                                 ushort_t* __restrict__ hb) {
  int lane = threadIdx.x & 63;
  int wid  = threadIdx.x >> 6;
  int lr = lane & 15, lg = lane >> 4;
  int rowblk  = blockIdx.x * 64 + (wid & 1) * 32;
  int colbase = (wid >> 1) * 160;
  int ar0 = rowblk + lr;       if (ar0 >= N_NODES) ar0 = 0;
  int ar1 = rowblk + 16 + lr;  if (ar1 >= N_NODES) ar1 = 0;
  f32x4 acc[2][10];
#pragma unroll
  for (int a = 0; a < 2; ++a)
#pragma unroll
    for (int c = 0; c < 10; ++c) acc[a][c] = (f32x4){0.f, 0.f, 0.f, 0.f};

#pragma unroll
  for (int ks = 0; ks < 2; ++ks) {
    int k0 = ks * 32;
    const float* xr0 = x + (size_t)ar0 * DIN_ + k0 + lg * 8;
    const float* xr1 = x + (size_t)ar1 * DIN_ + k0 + lg * 8;
    f32x4 l0 = *(const f32x4*)xr0, h0 = *(const f32x4*)(xr0 + 4);
    f32x4 l1 = *(const f32x4*)xr1, h1 = *(const f32x4*)(xr1 + 4);
    bf16x8 a0, a1;
#pragma unroll
    for (int j = 0; j < 4; ++j) {
      a0[j] = (short)f2b(l0[j]); a0[j + 4] = (short)f2b(h0[j]);
      a1[j] = (short)f2b(l1[j]); a1[j + 4] = (short)f2b(h1[j]);
    }
    const ushort_t* bb = Bpn + ((unsigned)(k0 / 8 + lg) * KPAD + colbase + lr) * 8;
#pragma unroll
    for (int c = 0; c < 10; ++c) {
      bf16x8 b = *(const bf16x8*)(bb + c * 16 * 8);
      acc[0][c] = __builtin_amdgcn_mfma_f32_16x16x32_bf16(a0, b, acc[0][c], 0, 0, 0);
      acc[1][c] = __builtin_amdgcn_mfma_f32_16x16x32_bf16(a1, b, acc[1][c], 0, 0, 0);
    }
  }
#pragma unroll
  for (int rt = 0; rt < 2; ++rt) {
#pragma unroll
    for (int c = 0; c < 10; ++c) {
      int col = colbase + c * 16 + lr;
      float bv = (col < H_) ? bpn[col] : 0.f;
#pragma unroll
      for (int r = 0; r < 4; ++r) {
        int row = rowblk + rt * 16 + lg * 4 + r;
        if (row >= N_NODES) continue;
        float v = fmaxf(acc[rt][c][r] + bv, 0.f);
        if (col >= H_) v = 0.f;
        hb[(unsigned)row * KPAD + col] = f2b(v);
      }
    }
  }
}

// ---------------- fused edge-MLP + aggregation (v2) ----------------
// zb[n][t] = bf16( hb[n][t] + sum_{p in CSR(n)} relu(hb[src_p][t] + (ea@Wpe+bpe)[t]) )
// Block = 1 node, 320 thr = 5 waves. Per 16-edge chunk:
//  phase 1: e-MLP via MFMA; result -> LDS[col][ESLOT] as packed b64 (4 edges/write);
//           invalid edge slots = bf16 -inf so relu(g + -inf) = 0 (mask-free phase 2).
//  phase 2: thread t owns col t; src ids broadcast via readlane (1 VMEM/chunk);
//           4x ds_read_b64 + 16 coalesced row-gathers; uniform quarter guard.
// Double-buffered LDS -> one __syncthreads per chunk.
__global__ __launch_bounds__(320) void node_agg_mfma(const ushort_t* __restrict__ hb,
                                                     const float* __restrict__ ea,
                                                     const ushort_t* __restrict__ Bpe,
                                                     const int* __restrict__ csr_src,
                                                     const int* __restrict__ csr_eid,
                                                     const int* __restrict__ off,
                                                     ushort_t* zb) {
  __shared__ ushort_t lds_e[2 * KPAD * ESLOT];  // 25.6 KB
  int n = blockIdx.x;
  int tid = threadIdx.x;
  if (n >= N_NODES) {
    zb[(unsigned)n * KPAD + tid] = 0;
    return;
  }
  int lane = tid & 63;
  int w = tid >> 6;  // wave 0..4
  int lr = lane & 15, lg = lane >> 4;
  int p0 = __builtin_amdgcn_readfirstlane(off[n]);
  int p1 = __builtin_amdgcn_readfirstlane(off[n + 1]);
  unsigned zi = (unsigned)n * KPAD + tid;
  float self = b2f(hb[zi]);

  // B-frags for this wave's 4 col-tiles (constant across chunks)
  bf16x8 bfr[4];
#pragma unroll
  for (int t = 0; t < 4; ++t) {
    int col = w * 64 + t * 16 + lr;
    bfr[t] = *(const bf16x8*)(Bpe + ((unsigned)lg * KPAD + col) * 8);
  }

  float acc = 0.f;
  int ci = 0;
  for (int pc = p0; pc < p1; pc += 16, ci ^= 1) {
    // ---- phase 1: e-MLP for up to 16 edges -> LDS (packed, -inf padded)
    int eid = csr_eid[pc + lr];
    bf16x8 afr = (bf16x8){0, 0, 0, 0, 0, 0, 0, 0};
    if (lg < 2) {
      const float* ar = ea + (size_t)eid * EIN_ + lg * 8;
      f32x4 lo = *(const f32x4*)ar;
      f32x4 hi = *(const f32x4*)(ar + 4);
#pragma unroll
      for (int j = 0; j < 4; ++j) {
        afr[j] = (short)f2b(lo[j]);
        afr[j + 4] = (short)f2b(hi[j]);
      }
    } else if (lg == 2) {
      afr[0] = (short)0x3F80;  // k==16 -> 1.0 selects bias row of Bpe
    }
    int ebase = lg * 4;
    ushort_t* ldsb = lds_e + ci * (KPAD * ESLOT);
#pragma unroll
    for (int t = 0; t < 4; ++t) {
      f32x4 e4 = __builtin_amdgcn_mfma_f32_16x16x32_bf16(afr, bfr[t], (f32x4){0.f, 0.f, 0.f, 0.f}, 0, 0, 0);
      int col = w * 64 + t * 16 + lr;
      s16x4 pk;
#pragma unroll
      for (int r = 0; r < 4; ++r)
        pk[r] = (short)((pc + ebase + r < p1) ? f2b(e4[r]) : (ushort_t)0xFF80);  // -inf pad
      *(s16x4*)(ldsb + (unsigned)col * ESLOT + ebase) = pk;
    }
    // src ids for the whole chunk, one load + readlane broadcast
    int sv = csr_src[pc + lr];
    __syncthreads();
    // ---- phase 2: per-col accumulate (col = tid), mask-free
    const ushort_t* ldsr = lds_e + ci * (KPAD * ESLOT) + (unsigned)tid * ESLOT;
#pragma unroll
    for (int eq = 0; eq < 4; ++eq) {
      if (pc + eq * 4 >= p1) break;  // uniform quarter guard
      s16x4 ep = *(const s16x4*)(ldsr + eq * 4);
#pragma unroll
      for (int r = 0; r < 4; ++r) {
        int s = __builtin_amdgcn_readlane(sv, eq * 4 + r);
        float g = b2f(hb[(unsigned)s * KPAD + tid]);
        acc += fmaxf(g + b2f((ushort_t)ep[r]), 0.f);
      }
    }
  }
  zb[zi] = f2b(self + acc);
}

// C = act(A @ W + bias).  A: bf16 [NPAD][320].  Bp: frag-packed bf16 [40][320][8].
// v2: 64 rows per wave (4 independent MFMA chains); block = 128 rows x 320 cols.
// Supports in-place A==Cout (block touches only rows [128b,128b+128);
// __syncthreads() separates all A-reads from C-writes).
template <int RELU_OUT, int OUT_BF16>
__global__ __launch_bounds__(256) void gemm300(const ushort_t* A,
                                               const ushort_t* __restrict__ Bp,
                                               const float* __restrict__ bias,
                                               void* Cout) {
  int lane = threadIdx.x & 63;
  int wid  = threadIdx.x >> 6;
  int lr = lane & 15, lg = lane >> 4;
  int rowblk  = blockIdx.x * 128 + (wid & 1) * 64;  // wave: 64 rows x 160 cols
  int colbase = (wid >> 1) * 160;
  f32x4 acc[4][10];
#pragma unroll
  for (int a = 0; a < 4; ++a)
#pragma unroll
    for (int c = 0; c < 10; ++c) acc[a][c] = (f32x4){0.f, 0.f, 0.f, 0.f};

  const ushort_t* Ap = A + (unsigned)(rowblk + lr) * KPAD + lg * 8;
  for (int k0 = 0; k0 < KPAD; k0 += 32) {
    bf16x8 a0 = *(const bf16x8*)(Ap + k0);
    bf16x8 a1 = *(const bf16x8*)(Ap + 16 * KPAD + k0);
    bf16x8 a2 = *(const bf16x8*)(Ap + 32 * KPAD + k0);
    bf16x8 a3 = *(const bf16x8*)(Ap + 48 * KPAD + k0);
    const ushort_t* bb = Bp + ((unsigned)(k0 / 8 + lg) * KPAD + colbase + lr) * 8;
#pragma unroll
    for (int c = 0; c < 10; ++c) {
      bf16x8 b = *(const bf16x8*)(bb + c * 16 * 8);
      acc[0][c] = __builtin_amdgcn_mfma_f32_16x16x32_bf16(a0, b, acc[0][c], 0, 0, 0);
      acc[1][c] = __builtin_amdgcn_mfma_f32_16x16x32_bf16(a1, b, acc[1][c], 0, 0, 0);
      acc[2][c] = __builtin_amdgcn_mfma_f32_16x16x32_bf16(a2, b, acc[2][c], 0, 0, 0);
      acc[3][c] = __builtin_amdgcn_mfma_f32_16x16x32_bf16(a3, b, acc[3][c], 0, 0, 0);
    }
  }
  __syncthreads();  // all A-reads done before any in-place C-write
  // epilogue: D mapping col=lane&15, row=(lane>>4)*4+r  [m89/m91]
#pragma unroll
  for (int rt = 0; rt < 4; ++rt) {
#pragma unroll
    for (int c = 0; c < 10; ++c) {
      int col = colbase + c * 16 + lr;
      float bv = (col < H_) ? bias[col] : 0.f;
#pragma unroll
      for (int r = 0; r < 4; ++r) {
        int row = rowblk + rt * 16 + lg * 4 + r;
        if (row >= N_NODES) continue;
        float v = acc[rt][c][r] + bv;
        if (RELU_OUT) v = fmaxf(v, 0.f);
        if (OUT_BF16) {
          ((ushort_t*)Cout)[(unsigned)row * KPAD + col] = f2b(v);
        } else if (col < H_) {
          ((float*)Cout)[(unsigned)row * H_ + col] = v;
        }
      }
    }
  }
}

// pooled[g] = sum of h rows with batch==g (batch sorted -> binary search bounds)
__global__ void pool_kernel(const float* __restrict__ h, const int* __restrict__ batch,
                            float* __restrict__ pooled) {
  int g = blockIdx.x;
  int hh = threadIdx.x;  // block 320
  int lo = 0, hi = N_NODES;
  while (lo < hi) { int mid = (lo + hi) >> 1; if (batch[mid] < g) lo = mid + 1; else hi = mid; }
  int start = lo;
  hi = N_NODES;
  while (lo < hi) { int mid = (lo + hi) >> 1; if (batch[mid] < g + 1) lo = mid + 1; else hi = mid; }
  int end = lo;
  if (hh >= H_) return;
  float s = 0.f;
  for (int n = start; n < end; ++n) s += h[(unsigned)n * H_ + hh];
  pooled[g * H_ + hh] = s;
}

// out = prelu(pooled @ W_sp + b_sp)
__global__ void final_kernel(const float* __restrict__ pooled, const float* __restrict__ Wsp,
                             const float* __restrict__ bsp, const float* __restrict__ pa,
                             float* __restrict__ out) {
  int f = blockIdx.x * 256 + threadIdx.x;
  if (f >= G_GR * R_OUT) return;
  int g = f >> 10, r = f & 1023;
  float acc = bsp[r];
  const float* pr = pooled + g * H_;
  const float* wc = Wsp + r;
  for (int k = 0; k < H_; ++k) acc += pr[k] * wc[k * R_OUT];
  float a = pa[0];
  out[f] = acc >= 0.f ? acc : a * acc;
}

extern "C" void kernel_launch(void* const* d_in, const int* in_sizes, int n_in,
                              void* d_out, int out_size, void* d_ws, size_t ws_size,
                              hipStream_t stream) {
  const float* x   = (const float*)d_in[0];
  const float* ea  = (const float*)d_in[1];
  const int*   ei  = (const int*)d_in[2];
  const int*   bat = (const int*)d_in[3];
  const float* Wpn = (const float*)d_in[4];
  const float* bpn = (const float*)d_in[5];
  const float* Wpe = (const float*)d_in[6];
  const float* bpe = (const float*)d_in[7];
  const float* W1  = (const float*)d_in[8];
  const float* b1  = (const float*)d_in[9];
  const float* W2  = (const float*)d_in[10];
  const float* b2  = (const float*)d_in[11];
  const float* Wsp = (const float*)d_in[12];
  const float* bsp = (const float*)d_in[13];
  const float* pa  = (const float*)d_in[14];
  const int* src = ei;
  const int* dst = ei + N_EDGES;

  char* ws = (char*)d_ws;
  size_t off_b = 0;
  auto alloc = [&](size_t bytes) {
    void* p = ws + off_b;
    off_b += (bytes + 255) & ~(size_t)255;
    return p;
  };
  ushort_t* hb      = (ushort_t*)alloc(sizeof(ushort_t) * (size_t)NPAD * KPAD);  // 32 MB
  ushort_t* zb      = (ushort_t*)alloc(sizeof(ushort_t) * (size_t)NPAD * KPAD);  // 32 MB
  float*    h       = (float*)alloc(sizeof(float) * (size_t)N_NODES * H_);       // 60 MB
  ushort_t* Bp1     = (ushort_t*)alloc(sizeof(ushort_t) * (size_t)DEPTH_ * 40 * KPAD * 8);
  ushort_t* Bp2     = (ushort_t*)alloc(sizeof(ushort_t) * (size_t)DEPTH_ * 40 * KPAD * 8);
  ushort_t* Bpe     = (ushort_t*)alloc(sizeof(ushort_t) * (size_t)4 * KPAD * 8);
  ushort_t* Bpn     = (ushort_t*)alloc(sizeof(ushort_t) * (size_t)8 * KPAD * 8);
  float*    pooled  = (float*)alloc(sizeof(float) * (size_t)G_GR * H_);
  int*      deg     = (int*)alloc(sizeof(int) * N_NODES);
  int*      offs    = (int*)alloc(sizeof(int) * (N_NODES + 1));
  int*      cursor  = (int*)alloc(sizeof(int) * N_NODES);
  int*      csr_src = (int*)alloc(sizeof(int) * (N_EDGES + 16));  // +16 zero pad
  int*      csr_eid = (int*)alloc(sizeof(int) * (N_EDGES + 16));  // +16 zero pad

  // ---- CSR build ----
  hipMemsetAsync(deg, 0, sizeof(int) * N_NODES, stream);
  hipMemsetAsync(csr_src + N_EDGES, 0, 16 * sizeof(int), stream);
  hipMemsetAsync(csr_eid + N_EDGES, 0, 16 * sizeof(int), stream);
  hist_deg<<<(N_EDGES + 255) / 256, 256, 0, stream>>>(dst, deg);
  exscan_kernel<<<1, 1024, 0, stream>>>(deg, offs);
  hipMemcpyAsync(cursor, offs, sizeof(int) * N_NODES, hipMemcpyDeviceToDevice, stream);
  scatter_edges<<<(N_EDGES + 255) / 256, 256, 0, stream>>>(src, dst, cursor, csr_src, csr_eid);

  pack_weights<<<(2 * DEPTH_ * 40 * KPAD * 8 + 255) / 256, 256, 0, stream>>>(W1, W2, Bp1, Bp2);
  pack_wpe<<<(4 * KPAD * 8 + 255) / 256, 256, 0, stream>>>(Wpe, bpe, Bpe);
  pack_wpn<<<(8 * KPAD * 8 + 255) / 256, 256, 0, stream>>>(Wpn, Bpn);
  proj_gemm<<<NPAD / 64, 256, 0, stream>>>(x, Bpn, bpn, hb);

  for (int i = 0; i < DEPTH_; ++i) {
    node_agg_mfma<<<NPAD, 320, 0, stream>>>(hb, ea, Bpe, csr_src, csr_eid, offs, zb);
    // in-place: zb = relu(zb @ W1 + b1)
    gemm300<1, 1><<<NPAD / 128, 256, 0, stream>>>(zb, Bp1 + (size_t)i * 40 * KPAD * 8, b1 + i * H_, zb);
    if (i < DEPTH_ - 1)
      gemm300<1, 1><<<NPAD / 128, 256, 0, stream>>>(zb, Bp2 + (size_t)i * 40 * KPAD * 8, b2 + i * H_, hb);
    else
      gemm300<0, 0><<<NPAD / 128, 256, 0, stream>>>(zb, Bp2 + (size_t)i * 40 * KPAD * 8, b2 + i * H_, h);
  }

  pool_kernel<<<G_GR, 320, 0, stream>>>(h, bat, pooled);
  final_kernel<<<(G_GR * R_OUT) / 256, 256, 0, stream>>>(pooled, Wsp, bsp, pa, (float*)d_out);
}

// Round 10
// 1792.831 us; speedup vs baseline: 1.1652x; 1.1652x over previous
//
#include <hip/hip_runtime.h>
#include <hip/hip_bf16.h>
#include <math.h>

#define N_NODES 50000
#define N_EDGES 800000
#define DIN_    64
#define EIN_    16
#define H_      300
#define R_OUT   1024
#define G_GR    256
#define DEPTH_  5
#define KPAD    320
#define NPAD    50048   // multiple of 128 >= N_NODES
#define ESLOT   20      // LDS slots per col (16 edges + pad), 8B-aligned rows

typedef unsigned short ushort_t;
typedef __attribute__((ext_vector_type(8))) short bf16x8;
typedef __attribute__((ext_vector_type(4))) short s16x4;
typedef __attribute__((ext_vector_type(4))) float f32x4;

__device__ __forceinline__ ushort_t f2b(float f) {
  unsigned x = __float_as_uint(f);
  unsigned r = (x + 0x7fffu + ((x >> 16) & 1u)) >> 16;  // RTN-even
  return (ushort_t)r;
}
__device__ __forceinline__ float b2f(ushort_t u) {
  return __uint_as_float((unsigned)u << 16);
}
// HW packed f32->bf16 (RNE), 1 instr / 2 values
__device__ __forceinline__ unsigned cvtpk(float lo, float hi) {
  unsigned r;
  asm("v_cvt_pk_bf16_f32 %0, %1, %2" : "=v"(r) : "v"(lo), "v"(hi));
  return r;
}

// ---------------- weight packing (once per call) ----------------
__global__ void pack_weights(const float* __restrict__ W1, const float* __restrict__ W2,
                             ushort_t* __restrict__ Bp1, ushort_t* __restrict__ Bp2) {
  int idx = blockIdx.x * 256 + threadIdx.x;
  const int per = DEPTH_ * 40 * KPAD * 8;  // 512000
  if (idx >= 2 * per) return;
  const float* W = W1;
  ushort_t* Bp = Bp1;
  int t = idx;
  if (t >= per) { t -= per; W = W2; Bp = Bp2; }
  int j  = t & 7;
  int n  = (t >> 3) % KPAD;
  int kg = ((t >> 3) / KPAD) % 40;
  int i  = t / (40 * KPAD * 8);
  int k  = kg * 8 + j;
  float v = (k < H_ && n < H_) ? W[(i * H_ + k) * H_ + n] : 0.f;
  Bp[t] = f2b(v);
}

// Pack Wpe (fp32 [16][300]) + bpe into frag layout Bpe[kg<4][n<320][j<8],
// K padded to 32 with k==16 row = bpe (bias folded via A k=16 element = 1.0).
__global__ void pack_wpe(const float* __restrict__ Wpe, const float* __restrict__ bpe,
                         ushort_t* __restrict__ Bpe) {
  int t = blockIdx.x * 256 + threadIdx.x;
  if (t >= 4 * KPAD * 8) return;
  int j  = t & 7;
  int n  = (t >> 3) % KPAD;
  int kg = (t >> 3) / KPAD;
  int k  = kg * 8 + j;
  float v = 0.f;
  if (n < H_) {
    if (k < EIN_) v = Wpe[k * H_ + n];
    else if (k == EIN_) v = bpe[n];
  }
  Bpe[t] = f2b(v);
}

// Pack Wpn (fp32 [64][300]) into frag layout Bpn[kg<8][n<320][j<8]
__global__ void pack_wpn(const float* __restrict__ Wpn, ushort_t* __restrict__ Bpn) {
  int t = blockIdx.x * 256 + threadIdx.x;
  if (t >= 8 * KPAD * 8) return;
  int j  = t & 7;
  int n  = (t >> 3) % KPAD;
  int kg = (t >> 3) / KPAD;
  int k  = kg * 8 + j;
  float v = (n < H_) ? Wpn[k * H_ + n] : 0.f;
  Bpn[t] = f2b(v);
}

// ---------------- CSR build (once per call) ----------------
__global__ void hist_deg(const int* __restrict__ dst, int* __restrict__ deg) {
  int e = blockIdx.x * 256 + threadIdx.x;
  if (e < N_EDGES) atomicAdd(deg + dst[e], 1);
}

__global__ __launch_bounds__(1024) void exscan_kernel(const int* __restrict__ deg,
                                                      int* __restrict__ off) {
  __shared__ int wsum[16];
  __shared__ int carry_s;
  int lane = threadIdx.x & 63;
  int wv = threadIdx.x >> 6;
  if (threadIdx.x == 0) carry_s = 0;
  __syncthreads();
  for (int base = 0; base < N_NODES; base += 1024) {
    int i = base + (int)threadIdx.x;
    int orig = (i < N_NODES) ? deg[i] : 0;
    int v = orig;
#pragma unroll
    for (int s = 1; s < 64; s <<= 1) {
      int u = __shfl_up(v, s);
      if (lane >= s) v += u;
    }
    if (lane == 63) wsum[wv] = v;
    __syncthreads();
    if (wv == 0) {
      int t = (lane < 16) ? wsum[lane] : 0;
#pragma unroll
      for (int s = 1; s < 16; s <<= 1) {
        int u = __shfl_up(t, s);
        if (lane >= s) t += u;
      }
      if (lane < 16) wsum[lane] = t;
    }
    __syncthreads();
    int wbase = (wv > 0) ? wsum[wv - 1] : 0;
    if (i < N_NODES) off[i] = carry_s + wbase + v - orig;
    __syncthreads();
    if (threadIdx.x == 1023) carry_s += wsum[15];
    __syncthreads();
  }
  if (threadIdx.x == 0) off[N_NODES] = carry_s;
}

__global__ void scatter_edges(const int* __restrict__ src, const int* __restrict__ dst,
                              int* __restrict__ cursor, int* __restrict__ csr_src,
                              int* __restrict__ csr_eid) {
  int e = blockIdx.x * 256 + threadIdx.x;
  if (e >= N_EDGES) return;
  int d = dst[e];
  int pos = atomicAdd(cursor + d, 1);
  csr_src[pos] = src[e];
  csr_eid[pos] = e;
}

// ---------------- input projection via MFMA ----------------
__global__ __launch_bounds__(256) void proj_gemm(const float* __restrict__ x,
                                                 const ushort_t* __restrict__ Bpn,
                                                 const float* __restrict__ bpn,
                                                 ushort_t* __restrict__ hb) {
  int lane = threadIdx.x & 63;
  int wid  = threadIdx.x >> 6;
  int lr = lane & 15, lg = lane >> 4;
  int rowblk  = blockIdx.x * 64 + (wid & 1) * 32;
  int colbase = (wid >> 1) * 160;
  int ar0 = rowblk + lr;       if (ar0 >= N_NODES) ar0 = 0;
  int ar1 = rowblk + 16 + lr;  if (ar1 >= N_NODES) ar1 = 0;
  f32x4 acc[2][10];
#pragma unroll
  for (int a = 0; a < 2; ++a)
#pragma unroll
    for (int c = 0; c < 10; ++c) acc[a][c] = (f32x4){0.f, 0.f, 0.f, 0.f};

#pragma unroll
  for (int ks = 0; ks < 2; ++ks) {
    int k0 = ks * 32;
    const float* xr0 = x + (size_t)ar0 * DIN_ + k0 + lg * 8;
    const float* xr1 = x + (size_t)ar1 * DIN_ + k0 + lg * 8;
    f32x4 l0 = *(const f32x4*)xr0, h0 = *(const f32x4*)(xr0 + 4);
    f32x4 l1 = *(const f32x4*)xr1, h1 = *(const f32x4*)(xr1 + 4);
    union { bf16x8 v; unsigned u[4]; } a0, a1;
    a0.u[0] = cvtpk(l0[0], l0[1]); a0.u[1] = cvtpk(l0[2], l0[3]);
    a0.u[2] = cvtpk(h0[0], h0[1]); a0.u[3] = cvtpk(h0[2], h0[3]);
    a1.u[0] = cvtpk(l1[0], l1[1]); a1.u[1] = cvtpk(l1[2], l1[3]);
    a1.u[2] = cvtpk(h1[0], h1[1]); a1.u[3] = cvtpk(h1[2], h1[3]);
    const ushort_t* bb = Bpn + ((unsigned)(k0 / 8 + lg) * KPAD + colbase + lr) * 8;
#pragma unroll
    for (int c = 0; c < 10; ++c) {
      bf16x8 b = *(const bf16x8*)(bb + c * 16 * 8);
      acc[0][c] = __builtin_amdgcn_mfma_f32_16x16x32_bf16(a0.v, b, acc[0][c], 0, 0, 0);
      acc[1][c] = __builtin_amdgcn_mfma_f32_16x16x32_bf16(a1.v, b, acc[1][c], 0, 0, 0);
    }
  }
#pragma unroll
  for (int rt = 0; rt < 2; ++rt) {
#pragma unroll
    for (int c = 0; c < 10; ++c) {
      int col = colbase + c * 16 + lr;
      float bv = (col < H_) ? bpn[col] : 0.f;
#pragma unroll
      for (int r = 0; r < 4; ++r) {
        int row = rowblk + rt * 16 + lg * 4 + r;
        if (row >= N_NODES) continue;
        float v = fmaxf(acc[rt][c][r] + bv, 0.f);
        if (col >= H_) v = 0.f;
        hb[(unsigned)row * KPAD + col] = f2b(v);
      }
    }
  }
}

// ---------------- fused edge-MLP + aggregation (v3) ----------------
// zb[n][t] = bf16( hb[n][t] + sum_{p in CSR(n)} relu(hb[src_p][t] + (ea@Wpe+bpe)[t]) )
// Per 16-edge chunk: phase 1 e-MLP via MFMA -> LDS[col][ESLOT] (b64 packed via
// v_cvt_pk_bf16_f32; invalid edges = -inf pre-pack so relu kills them);
// phase 2: thread t owns col t; src broadcast by readlane; 4x ds_read_b64 +
// 16 row-gathers. Double-buffered LDS, one barrier per chunk.
__global__ __launch_bounds__(320) void node_agg_mfma(const ushort_t* __restrict__ hb,
                                                     const float* __restrict__ ea,
                                                     const ushort_t* __restrict__ Bpe,
                                                     const int* __restrict__ csr_src,
                                                     const int* __restrict__ csr_eid,
                                                     const int* __restrict__ off,
                                                     ushort_t* zb) {
  __shared__ ushort_t lds_e[2 * KPAD * ESLOT];  // 25.6 KB
  int n = blockIdx.x;
  int tid = threadIdx.x;
  if (n >= N_NODES) {
    zb[(unsigned)n * KPAD + tid] = 0;
    return;
  }
  int lane = tid & 63;
  int w = tid >> 6;  // wave 0..4
  int lr = lane & 15, lg = lane >> 4;
  int p0 = __builtin_amdgcn_readfirstlane(off[n]);
  int p1 = __builtin_amdgcn_readfirstlane(off[n + 1]);
  unsigned zi = (unsigned)n * KPAD + tid;
  float self = b2f(hb[zi]);

  // B-frags for this wave's 4 col-tiles (constant across chunks)
  bf16x8 bfr[4];
#pragma unroll
  for (int t = 0; t < 4; ++t) {
    int col = w * 64 + t * 16 + lr;
    bfr[t] = *(const bf16x8*)(Bpe + ((unsigned)lg * KPAD + col) * 8);
  }

  float acc = 0.f;
  int ci = 0;
  for (int pc = p0; pc < p1; pc += 16, ci ^= 1) {
    // ---- phase 1: e-MLP for up to 16 edges -> LDS
    int eid = csr_eid[pc + lr];
    union { bf16x8 v; unsigned u[4]; } afr;
    afr.u[0] = afr.u[1] = afr.u[2] = afr.u[3] = 0u;
    if (lg < 2) {
      const float* ar = ea + (size_t)eid * EIN_ + lg * 8;
      f32x4 lo = *(const f32x4*)ar;
      f32x4 hi = *(const f32x4*)(ar + 4);
      afr.u[0] = cvtpk(lo[0], lo[1]); afr.u[1] = cvtpk(lo[2], lo[3]);
      afr.u[2] = cvtpk(hi[0], hi[1]); afr.u[3] = cvtpk(hi[2], hi[3]);
    } else if (lg == 2) {
      afr.u[0] = 0x3F80u;  // k==16 -> 1.0 selects bias row of Bpe
    }
    int ebase = lg * 4;
    // validity of this lg-group's 4 edge slots (chunk-constant)
    bool v0 = (pc + ebase + 0 < p1), v1 = (pc + ebase + 1 < p1);
    bool v2 = (pc + ebase + 2 < p1), v3 = (pc + ebase + 3 < p1);
    ushort_t* ldsb = lds_e + ci * (KPAD * ESLOT);
#pragma unroll
    for (int t = 0; t < 4; ++t) {
      f32x4 e4 = __builtin_amdgcn_mfma_f32_16x16x32_bf16(afr.v, bfr[t], (f32x4){0.f, 0.f, 0.f, 0.f}, 0, 0, 0);
      int col = w * 64 + t * 16 + lr;
      float f0 = v0 ? e4[0] : -INFINITY;
      float f1 = v1 ? e4[1] : -INFINITY;
      float f2 = v2 ? e4[2] : -INFINITY;
      float f3 = v3 ? e4[3] : -INFINITY;
      union { s16x4 v; unsigned u[2]; } pk;
      pk.u[0] = cvtpk(f0, f1);
      pk.u[1] = cvtpk(f2, f3);
      *(s16x4*)(ldsb + (unsigned)col * ESLOT + ebase) = pk.v;
    }
    // src ids for the whole chunk, one load + readlane broadcast
    int sv = csr_src[pc + lr];
    __syncthreads();
    // ---- phase 2: per-col accumulate (col = tid), mask-free
    const ushort_t* ldsr = lds_e + ci * (KPAD * ESLOT) + (unsigned)tid * ESLOT;
#pragma unroll
    for (int eq = 0; eq < 4; ++eq) {
      if (pc + eq * 4 >= p1) break;  // uniform quarter guard
      s16x4 ep = *(const s16x4*)(ldsr + eq * 4);
#pragma unroll
      for (int r = 0; r < 4; ++r) {
        int s = __builtin_amdgcn_readlane(sv, eq * 4 + r);
        float g = b2f(hb[(unsigned)s * KPAD + tid]);
        acc += fmaxf(g + b2f((ushort_t)ep[r]), 0.f);
      }
    }
  }
  zb[zi] = f2b(self + acc);
}

// C = act(A @ W + bias).  A: bf16 [NPAD][320].  Bp: frag-packed bf16 [40][320][8].
// v1 (proven): 32 rows/wave, block 256 = 64 rows x 320 cols. Supports in-place
// A==Cout (block touches only rows [64b,64b+64); barrier before C-writes).
template <int RELU_OUT, int OUT_BF16>
__global__ __launch_bounds__(256) void gemm300(const ushort_t* A,
                                               const ushort_t* __restrict__ Bp,
                                               const float* __restrict__ bias,
                                               void* Cout) {
  int lane = threadIdx.x & 63;
  int wid  = threadIdx.x >> 6;
  int lr = lane & 15, lg = lane >> 4;
  int rowblk  = blockIdx.x * 64 + (wid & 1) * 32;  // wave: 32 rows x 160 cols
  int colbase = (wid >> 1) * 160;
  f32x4 acc[2][10];
#pragma unroll
  for (int a = 0; a < 2; ++a)
#pragma unroll
    for (int c = 0; c < 10; ++c) acc[a][c] = (f32x4){0.f, 0.f, 0.f, 0.f};

  const ushort_t* Ap = A + (unsigned)(rowblk + lr) * KPAD + lg * 8;
  for (int k0 = 0; k0 < KPAD; k0 += 32) {
    bf16x8 a0 = *(const bf16x8*)(Ap + k0);
    bf16x8 a1 = *(const bf16x8*)(Ap + 16 * KPAD + k0);
    const ushort_t* bb = Bp + ((unsigned)(k0 / 8 + lg) * KPAD + colbase + lr) * 8;
#pragma unroll
    for (int c = 0; c < 10; ++c) {
      bf16x8 b = *(const bf16x8*)(bb + c * 16 * 8);
      acc[0][c] = __builtin_amdgcn_mfma_f32_16x16x32_bf16(a0, b, acc[0][c], 0, 0, 0);
      acc[1][c] = __builtin_amdgcn_mfma_f32_16x16x32_bf16(a1, b, acc[1][c], 0, 0, 0);
    }
  }
  __syncthreads();  // all A-reads done before any in-place C-write
  // epilogue: D mapping col=lane&15, row=(lane>>4)*4+r  [m89/m91]
#pragma unroll
  for (int rt = 0; rt < 2; ++rt) {
#pragma unroll
    for (int c = 0; c < 10; ++c) {
      int col = colbase + c * 16 + lr;
      float bv = (col < H_) ? bias[col] : 0.f;
#pragma unroll
      for (int r = 0; r < 4; ++r) {
        int row = rowblk + rt * 16 + lg * 4 + r;
        if (row >= N_NODES) continue;
        float v = acc[rt][c][r] + bv;
        if (RELU_OUT) v = fmaxf(v, 0.f);
        if (OUT_BF16) {
          ((ushort_t*)Cout)[(unsigned)row * KPAD + col] = f2b(v);
        } else if (col < H_) {
          ((float*)Cout)[(unsigned)row * H_ + col] = v;
        }
      }
    }
  }
}

// pooled4[q][g][hh] = partial sum over quarter q of group g's rows
__global__ void pool_kernel(const float* __restrict__ h, const int* __restrict__ batch,
                            float* __restrict__ pooled4) {
  int g = blockIdx.x >> 2;
  int q = blockIdx.x & 3;
  int hh = threadIdx.x;  // block 320
  int lo = 0, hi = N_NODES;
  while (lo < hi) { int mid = (lo + hi) >> 1; if (batch[mid] < g) lo = mid + 1; else hi = mid; }
  int start = lo;
  hi = N_NODES;
  while (lo < hi) { int mid = (lo + hi) >> 1; if (batch[mid] < g + 1) lo = mid + 1; else hi = mid; }
  int end = lo;
  if (hh >= H_) return;
  int len = end - start;
  int chunk = (len + 3) >> 2;
  int s = start + q * chunk;
  int e = s + chunk; if (e > end) e = end;
  float sum = 0.f;
  for (int n = s; n < e; ++n) sum += h[(unsigned)n * H_ + hh];
  pooled4[((unsigned)q * G_GR + g) * H_ + hh] = sum;
}

__global__ void pool_combine(const float* __restrict__ pooled4, float* __restrict__ pooled) {
  int f = blockIdx.x * 256 + threadIdx.x;
  if (f >= G_GR * H_) return;
  float s = pooled4[f] + pooled4[G_GR * H_ + f] + pooled4[2 * G_GR * H_ + f] + pooled4[3 * G_GR * H_ + f];
  pooled[f] = s;
}

// out = prelu(pooled @ W_sp + b_sp)
__global__ void final_kernel(const float* __restrict__ pooled, const float* __restrict__ Wsp,
                             const float* __restrict__ bsp, const float* __restrict__ pa,
                             float* __restrict__ out) {
  int f = blockIdx.x * 256 + threadIdx.x;
  if (f >= G_GR * R_OUT) return;
  int g = f >> 10, r = f & 1023;
  float acc = bsp[r];
  const float* pr = pooled + g * H_;
  const float* wc = Wsp + r;
  for (int k = 0; k < H_; ++k) acc += pr[k] * wc[k * R_OUT];
  float a = pa[0];
  out[f] = acc >= 0.f ? acc : a * acc;
}

extern "C" void kernel_launch(void* const* d_in, const int* in_sizes, int n_in,
                              void* d_out, int out_size, void* d_ws, size_t ws_size,
                              hipStream_t stream) {
  const float* x   = (const float*)d_in[0];
  const float* ea  = (const float*)d_in[1];
  const int*   ei  = (const int*)d_in[2];
  const int*   bat = (const int*)d_in[3];
  const float* Wpn = (const float*)d_in[4];
  const float* bpn = (const float*)d_in[5];
  const float* Wpe = (const float*)d_in[6];
  const float* bpe = (const float*)d_in[7];
  const float* W1  = (const float*)d_in[8];
  const float* b1  = (const float*)d_in[9];
  const float* W2  = (const float*)d_in[10];
  const float* b2  = (const float*)d_in[11];
  const float* Wsp = (const float*)d_in[12];
  const float* bsp = (const float*)d_in[13];
  const float* pa  = (const float*)d_in[14];
  const int* src = ei;
  const int* dst = ei + N_EDGES;

  char* ws = (char*)d_ws;
  size_t off_b = 0;
  auto alloc = [&](size_t bytes) {
    void* p = ws + off_b;
    off_b += (bytes + 255) & ~(size_t)255;
    return p;
  };
  ushort_t* hb      = (ushort_t*)alloc(sizeof(ushort_t) * (size_t)NPAD * KPAD);  // 32 MB
  ushort_t* zb      = (ushort_t*)alloc(sizeof(ushort_t) * (size_t)NPAD * KPAD);  // 32 MB
  float*    h       = (float*)alloc(sizeof(float) * (size_t)N_NODES * H_);       // 60 MB
  ushort_t* Bp1     = (ushort_t*)alloc(sizeof(ushort_t) * (size_t)DEPTH_ * 40 * KPAD * 8);
  ushort_t* Bp2     = (ushort_t*)alloc(sizeof(ushort_t) * (size_t)DEPTH_ * 40 * KPAD * 8);
  ushort_t* Bpe     = (ushort_t*)alloc(sizeof(ushort_t) * (size_t)4 * KPAD * 8);
  ushort_t* Bpn     = (ushort_t*)alloc(sizeof(ushort_t) * (size_t)8 * KPAD * 8);
  float*    pooled  = (float*)alloc(sizeof(float) * (size_t)G_GR * H_);
  float*    pooled4 = (float*)alloc(sizeof(float) * (size_t)4 * G_GR * H_);
  int*      deg     = (int*)alloc(sizeof(int) * N_NODES);
  int*      offs    = (int*)alloc(sizeof(int) * (N_NODES + 1));
  int*      cursor  = (int*)alloc(sizeof(int) * N_NODES);
  int*      csr_src = (int*)alloc(sizeof(int) * (N_EDGES + 16));  // +16 zero pad
  int*      csr_eid = (int*)alloc(sizeof(int) * (N_EDGES + 16));  // +16 zero pad

  // ---- CSR build ----
  hipMemsetAsync(deg, 0, sizeof(int) * N_NODES, stream);
  hipMemsetAsync(csr_src + N_EDGES, 0, 16 * sizeof(int), stream);
  hipMemsetAsync(csr_eid + N_EDGES, 0, 16 * sizeof(int), stream);
  hist_deg<<<(N_EDGES + 255) / 256, 256, 0, stream>>>(dst, deg);
  exscan_kernel<<<1, 1024, 0, stream>>>(deg, offs);
  hipMemcpyAsync(cursor, offs, sizeof(int) * N_NODES, hipMemcpyDeviceToDevice, stream);
  scatter_edges<<<(N_EDGES + 255) / 256, 256, 0, stream>>>(src, dst, cursor, csr_src, csr_eid);

  pack_weights<<<(2 * DEPTH_ * 40 * KPAD * 8 + 255) / 256, 256, 0, stream>>>(W1, W2, Bp1, Bp2);
  pack_wpe<<<(4 * KPAD * 8 + 255) / 256, 256, 0, stream>>>(Wpe, bpe, Bpe);
  pack_wpn<<<(8 * KPAD * 8 + 255) / 256, 256, 0, stream>>>(Wpn, Bpn);
  proj_gemm<<<NPAD / 64, 256, 0, stream>>>(x, Bpn, bpn, hb);

  for (int i = 0; i < DEPTH_; ++i) {
    node_agg_mfma<<<NPAD, 320, 0, stream>>>(hb, ea, Bpe, csr_src, csr_eid, offs, zb);
    // in-place: zb = relu(zb @ W1 + b1)
    gemm300<1, 1><<<NPAD / 64, 256, 0, stream>>>(zb, Bp1 + (size_t)i * 40 * KPAD * 8, b1 + i * H_, zb);
    if (i < DEPTH_ - 1)
      gemm300<1, 1><<<NPAD / 64, 256, 0, stream>>>(zb, Bp2 + (size_t)i * 40 * KPAD * 8, b2 + i * H_, hb);
    else
      gemm300<0, 0><<<NPAD / 64, 256, 0, stream>>>(zb, Bp2 + (size_t)i * 40 * KPAD * 8, b2 + i * H_, h);
  }

  pool_kernel<<<G_GR * 4, 320, 0, stream>>>(h, bat, pooled4);
  pool_combine<<<(G_GR * H_ + 255) / 256, 256, 0, stream>>>(pooled4, pooled);
  final_kernel<<<(G_GR * R_OUT) / 256, 256, 0, stream>>>(pooled, Wsp, bsp, pa, (float*)d_out);
}